// Round 12
// baseline (482.741 us; speedup 1.0000x reference)
//
#include <hip/hip_runtime.h>
#include <hip/hip_bf16.h>

namespace {

constexpr int Bn   = 32;
constexpr int IMG  = 48;
constexpr int Dm   = 384;
constexpr int NHn  = 8;
constexpr int WSn  = 6;
constexpr int NWn  = 64;          // 8x8 windows
constexpr int Mn   = Bn * NWn;    // 2048 windows
constexpr int Vn   = 36;          // tokens per window
constexpr int ROWS = Mn * Vn;     // 73728 token rows
constexpr int K3   = 3 * Dm;      // 1152
constexpr int HEADS_E = Vn * 48;  // 1728 elems per (m,h) tile
constexpr float SCALE = 0.14433756729740643f;  // 48^-0.5

using short8 = __attribute__((ext_vector_type(8))) short;
using f32x4  = __attribute__((ext_vector_type(4))) float;

__device__ __forceinline__ float bf2f(unsigned short u) {
    return __uint_as_float(((unsigned)u) << 16);
}
__device__ __forceinline__ unsigned short f2bf(float f) {
    unsigned u = __float_as_uint(f);
    u += 0x7FFFu + ((u >> 16) & 1u);   // RNE
    return (unsigned short)(u >> 16);
}

// 64-slot involution: low 3 bits ^= high 3 bits. Self-inverse.
// Verified R5/R6/R9/R10: SQ_LDS_BANK_CONFLICT ~0, results exact.
__device__ __forceinline__ int invol(int f) {
    return (f & 56) | ((f ^ (f >> 3)) & 7);
}

// async global->LDS, 16B per lane; LDS dest = wave-uniform base + lane*16
__device__ __forceinline__ void gl_lds16(const unsigned short* g, unsigned short* l) {
    __builtin_amdgcn_global_load_lds(
        (const __attribute__((address_space(1))) unsigned int*)g,
        (__attribute__((address_space(3))) unsigned int*)l, 16, 0, 0);
}

// row -> gathered source base (roll(-3) + window partition), in elements
__device__ __forceinline__ int gather_base(int row) {
    int m = row / Vn, v = row - m * Vn;
    int b = m >> 6, w = m & 63;
    int wh = w >> 3, ww = w & 7;
    int gh = wh * WSn + v / WSn;
    int gw = ww * WSn + v % WSn;
    int fi = (gh + 3) % IMG;
    int fj = (gw + 3) % IMG;
    return ((b * IMG + fi) * IMG + fj) * Dm;
}

// region id of token t in window (wh, ww)
__device__ __forceinline__ int region_id(int t, int wh, int ww) {
    int hi = (wh == 7) ? ((t / 6) < 3) : 1;
    int lo = (ww == 7) ? ((t % 6) < 3) : 1;
    return (hi << 1) | lo;
}

// ---------------------------------------------------------------------------
// gather_x: xg[row][k] = bf16(x[gathered(row)][k]); 4 elems/thread
// ---------------------------------------------------------------------------
__global__ __launch_bounds__(256)
void gather_x(const float* __restrict__ x, unsigned short* __restrict__ xg)
{
    int idx = blockIdx.x * 256 + threadIdx.x;      // ROWS*96 total
    int row = idx / 96;
    int c4  = (idx - row * 96) * 4;
    float4 v = *(const float4*)(x + (size_t)gather_base(row) + c4);
    ushort4 o;
    o.x = f2bf(v.x); o.y = f2bf(v.y); o.z = f2bf(v.z); o.w = f2bf(v.w);
    *(ushort4*)(xg + (size_t)row * Dm + c4) = o;
}

// ---------------------------------------------------------------------------
// prep_w: wqT[n][k] = bf16(wq[k][n]);  wpT[n][k] = bf16(wp[k][n])
// ---------------------------------------------------------------------------
__global__ __launch_bounds__(256)
void prep_w(const float* __restrict__ wq, const float* __restrict__ wp,
            unsigned short* __restrict__ wqT, unsigned short* __restrict__ wpT)
{
    int idx = blockIdx.x * 256 + threadIdx.x;
    if (idx < K3 * Dm) {
        int n = idx / Dm, k = idx - n * Dm;
        wqT[idx] = f2bf(wq[(size_t)k * K3 + n]);
    } else {
        int i2 = idx - K3 * Dm;
        if (i2 < Dm * Dm) {
            int n = i2 / Dm, k = i2 - n * Dm;
            wpT[i2] = f2bf(wp[(size_t)k * Dm + n]);
        }
    }
}

// ---------------------------------------------------------------------------
// qkv_mfma: R9 version, unchanged (control). ~115-118 us regardless of
// schedule: near its write/traffic floor within this decomposition.
// ---------------------------------------------------------------------------
__global__ __launch_bounds__(256)
void qkv_mfma(const unsigned short* __restrict__ xg,
              const unsigned short* __restrict__ wqT,
              const float* __restrict__ bq,
              unsigned short* __restrict__ qh,
              unsigned short* __restrict__ kh,
              unsigned short* __restrict__ vh)
{
    __shared__ __align__(16) unsigned short As[3][128 * 32];   // 24 KB
    __shared__ __align__(16) unsigned short Bs[3][128 * 32];   // 24 KB

    const int tid  = threadIdx.x;
    const int wave = tid >> 6, lane = tid & 63;
    const int quad = lane >> 4, l15 = lane & 15;
    // bijective XCD swizzle: grid = 5184 = 8 * 648
    const int id = (blockIdx.x & 7) * 648 + (blockIdx.x >> 3);
    const int nT = id % (K3 / 128);   // 9
    const int mT = id / (K3 / 128);
    const int rowA0 = mT * 128, rowB0 = nT * 128;

    const int fS  = invol(lane);
    const int rS  = fS >> 2;
    const int kcS = (fS & 3) * 8;
    const unsigned short* gA = xg  + (size_t)(rowA0 + wave * 32 + rS) * Dm + kcS;
    const unsigned short* gB = wqT + (size_t)(rowB0 + wave * 32 + rS) * Dm + kcS;

    const int wm = wave >> 1, wn = wave & 1;
    int aoff[4], boff[4];
#pragma unroll
    for (int i = 0; i < 4; i++) {
        int R = wm * 64 + i * 16 + l15;
        aoff[i] = (R >> 4) * 512 + invol((R & 15) * 4 + quad) * 8;
        int S = wn * 64 + i * 16 + l15;
        boff[i] = (S >> 4) * 512 + invol((S & 15) * 4 + quad) * 8;
    }

    f32x4 acc[4][4];
#pragma unroll
    for (int i = 0; i < 4; i++)
#pragma unroll
        for (int j = 0; j < 4; j++) acc[i][j] = (f32x4){0.f, 0.f, 0.f, 0.f};

    auto STAGE = [&](int buf, int k0) {
        gl_lds16(gA + k0,           &As[buf][(wave * 32) * 32]);
        gl_lds16(gA + 16 * Dm + k0, &As[buf][(wave * 32 + 16) * 32]);
        gl_lds16(gB + k0,           &Bs[buf][(wave * 32) * 32]);
        gl_lds16(gB + 16 * Dm + k0, &Bs[buf][(wave * 32 + 16) * 32]);
    };
    auto COMPUTE = [&](int buf) {
        short8 af[4], bfr[4];
#pragma unroll
        for (int i = 0; i < 4; i++) af[i]  = *(const short8*)&As[buf][aoff[i]];
#pragma unroll
        for (int j = 0; j < 4; j++) bfr[j] = *(const short8*)&Bs[buf][boff[j]];
#pragma unroll
        for (int i = 0; i < 4; i++)
#pragma unroll
            for (int j = 0; j < 4; j++)
                acc[i][j] = __builtin_amdgcn_mfma_f32_16x16x32_bf16(af[i], bfr[j], acc[i][j], 0, 0, 0);
    };

    STAGE(0, 0);
    STAGE(1, 32);
#pragma unroll
    for (int t = 0; t < 10; ++t) {
        asm volatile("s_waitcnt vmcnt(4)" ::: "memory");
        __builtin_amdgcn_s_barrier();
        STAGE((t + 2) % 3, (t + 2) * 32);
        COMPUTE(t % 3);
    }
    asm volatile("s_waitcnt vmcnt(4)" ::: "memory");
    __builtin_amdgcn_s_barrier();
    COMPUTE(10 % 3);
    asm volatile("s_waitcnt vmcnt(0)" ::: "memory");
    __builtin_amdgcn_s_barrier();
    COMPUTE(11 % 3);

    unsigned short* outb = (nT < 3) ? qh : (nT < 6) ? kh : vh;
    const int csub = (nT < 3) ? 0 : (nT < 6) ? 384 : 768;
#pragma unroll
    for (int j = 0; j < 4; j++) {
        int col = rowB0 + wn * 64 + j * 16 + l15;
        float b = bq[col];
        int c  = col - csub;
        int hh = c / 48, dd = c - hh * 48;
#pragma unroll
        for (int i = 0; i < 4; i++) {
#pragma unroll
            for (int r = 0; r < 4; r++) {
                int row = rowA0 + wm * 64 + i * 16 + quad * 4 + r;
                int mm = row / 36, vv = row - mm * 36;
                outb[((size_t)(mm * 8 + hh) * 36 + vv) * 48 + dd] = f2bf(acc[i][j][r] + b);
            }
        }
    }
}

// ---------------------------------------------------------------------------
// attn_proj (FUSED): R11 structure with the launch_bounds(256,3) pin REMOVED.
// R11 post-mortem: pinning to 3 waves/EU squeezed the allocator (VGPR 116->84
// reported) and spilled the hoisted fragments to scratch (WRITE +28.7 MB,
// FETCH +11.3 MB of spill traffic). LDS (46.6 KB -> 3 blocks/CU) is the
// binding occupancy limit anyway, so the pin bought nothing. This round
// re-tests T14 hoist + wave-private-barrier removal WITHOUT spills.
// ---------------------------------------------------------------------------
__global__ __launch_bounds__(256)
void attn_proj(const unsigned short* __restrict__ qh,
               const unsigned short* __restrict__ kh,
               const unsigned short* __restrict__ vh,
               const unsigned short* __restrict__ wpT,
               const float* __restrict__ bp,
               float* __restrict__ out)
{
    // union region: phase1 = Pl[4][48*56] (10752) + Vt[4][48*64] (12288)
    //               phase2 = attL[12*3*512] (18432)  -- aliases from elem 0
    __shared__ __align__(16) unsigned short SMEM[23040];   // 46.08 KB
    __shared__ int rowOut36[36];

    const int tid  = threadIdx.x;
    const int wave = tid >> 6, lane = tid & 63;
    const int quad = lane >> 4, l15 = lane & 15;
    const int m = blockIdx.x;
    const int w = m & 63, wh = w >> 3, ww = w & 7;
    const bool need_mask = (wh == 7) || (ww == 7);

    if (tid < 36) rowOut36[tid] = gather_base(m * 36 + tid);

    unsigned short* Plw = SMEM + wave * 2688;              // [48*56]
    unsigned short* vws = SMEM + 10752 + wave * 3072;      // [48*64]

    const short8 zf = {0, 0, 0, 0, 0, 0, 0, 0};

    // zero all Vt so tokens [36,64) read back 0.0
    {
        short8* vz = (short8*)(SMEM + 10752);
#pragma unroll
        for (int z = 0; z < 6; z++) vz[z * 256 + tid] = zf;
    }
    __syncthreads();

    const size_t hb0 = (size_t)(m * 8 + wave * 2 + 0) * HEADS_E;
    const size_t hb1 = (size_t)(m * 8 + wave * 2 + 1) * HEADS_E;

    auto LOADQK = [&](size_t hb, short8 (*qf)[2], short8 (*kf)[2]) {
        const unsigned short* qb = qh + hb;
        const unsigned short* kb = kh + hb;
#pragma unroll
        for (int t = 0; t < 3; t++) {
            const unsigned short* qr = qb + (t * 16 + l15) * 48;
            qf[t][0] = *(const short8*)(qr + quad * 8);
            qf[t][1] = (quad < 2) ? *(const short8*)(qr + 32 + quad * 8) : zf;
            const unsigned short* kr = kb + (t * 16 + l15) * 48;
            kf[t][0] = *(const short8*)(kr + quad * 8);
            kf[t][1] = *(const short8*)(kr + 32 + quad * 8);
        }
    };
    auto LOADV = [&](size_t hb, short8* vvr) {
        const unsigned short* vb = vh + hb;
#pragma unroll
        for (int p = 0; p < 4; p++) {
            int c = p * 64 + lane;                 // 216 16B-chunks
            if (c < 216) vvr[p] = *(const short8*)(vb + c * 8);
        }
    };
    auto WRITEV = [&](const short8* vvr) {
#pragma unroll
        for (int p = 0; p < 4; p++) {
            int c = p * 64 + lane;
            if (c < 216) {
                int v  = c / 6, d0 = (c - v * 6) * 8;
                int g  = v >> 3, v7 = v & 7;
#pragma unroll
                for (int jj = 0; jj < 8; jj++) {
                    int d = d0 + jj;
                    int slot = (g + (d & 7) + (d >> 3)) & 7;
                    vws[d * 64 + slot * 8 + v7] = (unsigned short)vvr[p][jj];
                }
            }
        }
    };
    auto QKT_SM = [&](short8 (*qf)[2], short8 (*kf)[2]) {
        f32x4 sacc[3][3];
#pragma unroll
        for (int i = 0; i < 3; i++)
#pragma unroll
            for (int j = 0; j < 3; j++) sacc[i][j] = (f32x4){0.f, 0.f, 0.f, 0.f};
        __builtin_amdgcn_s_setprio(1);
#pragma unroll
        for (int i = 0; i < 3; i++)
#pragma unroll
            for (int j = 0; j < 3; j++) {
                sacc[i][j] = __builtin_amdgcn_mfma_f32_16x16x32_bf16(qf[i][0], kf[j][0], sacc[i][j], 0, 0, 0);
                sacc[i][j] = __builtin_amdgcn_mfma_f32_16x16x32_bf16(qf[i][1], kf[j][1], sacc[i][j], 0, 0, 0);
            }
        __builtin_amdgcn_s_setprio(0);
#pragma unroll
        for (int i = 0; i < 3; i++) {
            float rs[4] = {0.f, 0.f, 0.f, 0.f};
            if (need_mask) {
#pragma unroll
                for (int j = 0; j < 3; j++) {
                    int C = j * 16 + l15;
                    int idc = region_id(C, wh, ww);
#pragma unroll
                    for (int r = 0; r < 4; r++) {
                        int R = i * 16 + quad * 4 + r;
                        int idr = region_id(R, wh, ww);
                        float s = sacc[i][j][r] * SCALE;
                        s = (C >= 36 || idr != idc) ? -1e30f : fminf(s, 30.f);
                        float e = __expf(s);
                        sacc[i][j][r] = e;
                        rs[r] += e;
                    }
                }
            } else {
#pragma unroll
                for (int j = 0; j < 3; j++) {
                    int C = j * 16 + l15;
#pragma unroll
                    for (int r = 0; r < 4; r++) {
                        float s = sacc[i][j][r] * SCALE;
                        s = (C >= 36) ? -1e30f : fminf(s, 30.f);
                        float e = __expf(s);
                        sacc[i][j][r] = e;
                        rs[r] += e;
                    }
                }
            }
#pragma unroll
            for (int r = 0; r < 4; r++) {
#pragma unroll
                for (int d = 1; d < 16; d <<= 1) rs[r] += __shfl_xor(rs[r], d, 16);
                rs[r] = 1.f / rs[r];
            }
#pragma unroll
            for (int j = 0; j < 3; j++)
#pragma unroll
                for (int r = 0; r < 4; r++) {
                    int R = i * 16 + quad * 4 + r;
                    int C = j * 16 + l15;
                    Plw[R * 56 + C] = f2bf(sacc[i][j][r] * rs[r]);
                }
        }
    };
    auto PV = [&](f32x4 (*oacc)[3]) {
        short8 pf[3][2], vf[3][2];
#pragma unroll
        for (int t = 0; t < 3; t++) {
            const unsigned short* pr = &Plw[(t * 16 + l15) * 56];
            pf[t][0] = *(const short8*)(pr + quad * 8);
            pf[t][1] = (quad < 2) ? *(const short8*)(pr + 32 + quad * 8) : zf;
            int d  = t * 16 + l15;
            int sb = (d & 7) + (d >> 3);
            vf[t][0] = *(const short8*)(vws + d * 64 + (((quad + sb) & 7) * 8));
            vf[t][1] = *(const short8*)(vws + d * 64 + (((quad + 4 + sb) & 7) * 8));
        }
#pragma unroll
        for (int i = 0; i < 3; i++)
#pragma unroll
            for (int j = 0; j < 3; j++) oacc[i][j] = (f32x4){0.f, 0.f, 0.f, 0.f};
        __builtin_amdgcn_s_setprio(1);
#pragma unroll
        for (int i = 0; i < 3; i++)
#pragma unroll
            for (int j = 0; j < 3; j++) {
                oacc[i][j] = __builtin_amdgcn_mfma_f32_16x16x32_bf16(pf[i][0], vf[j][0], oacc[i][j], 0, 0, 0);
                oacc[i][j] = __builtin_amdgcn_mfma_f32_16x16x32_bf16(pf[i][1], vf[j][1], oacc[i][j], 0, 0, 0);
            }
        __builtin_amdgcn_s_setprio(0);
    };

    f32x4 oacc2[2][3][3];
    short8 qf0[3][2], kf0[3][2], qf1[3][2], kf1[3][2];
    short8 vv0[4], vv1[4];

    LOADQK(hb0, qf0, kf0);
    LOADQK(hb1, qf1, kf1);       // T14: head-1 Q/K in flight under head-0 compute
    LOADV(hb0, vv0);
    WRITEV(vv0);                 // vws <- V0
    QKT_SM(qf0, kf0);            // scores0 -> Plw
    LOADV(hb1, vv1);             // T14: head-1 V in flight under PV0
    PV(oacc2[0]);                // reads Plw, vws (compiler-ordered lgkm)
    WRITEV(vv1);                 // vws <- V1 (per-wave LDS FIFO after PV0 reads)
    QKT_SM(qf1, kf1);            // overwrites Plw (after PV0's pf reads)
    PV(oacc2[1]);

    __syncthreads();   // ALL waves done with Pl/Vt -> safe to alias as attL

    // ---- write att rows into attL (invol-chunk layout, rows<36 only) ----
#pragma unroll
    for (int hi = 0; hi < 2; hi++) {
        const int h = wave * 2 + hi;
#pragma unroll
        for (int i = 0; i < 3; i++)
#pragma unroll
            for (int r = 0; r < 4; r++) {
                int R = i * 16 + quad * 4 + r;
                if (R < 36) {
                    int band = R >> 4, f4 = (R & 15) * 4;
#pragma unroll
                    for (int j = 0; j < 3; j++) {
                        int k  = h * 48 + j * 16 + l15;
                        int ks = k >> 5, kk = k & 31;
                        SMEM[(ks * 3 + band) * 512 + invol(f4 + (kk >> 3)) * 8 + (kk & 7)]
                            = f2bf(oacc2[hi][i][j][r]);
                    }
                }
            }
    }
    __syncthreads();   // attL visible to all waves

    // ---- proj: pacc = attL @ wpT^T ; wave owns cols [wave*96, +96) ----
    const int aoffP = invol(l15 * 4 + quad) * 8;
    const unsigned short* gBp = wpT + (size_t)(wave * 96 + l15) * 384 + quad * 8;
    f32x4 pacc[3][6];
#pragma unroll
    for (int i = 0; i < 3; i++)
#pragma unroll
        for (int j = 0; j < 6; j++) pacc[i][j] = (f32x4){0.f, 0.f, 0.f, 0.f};

#pragma unroll
    for (int ks = 0; ks < 12; ks++) {
        short8 bfr[6];
#pragma unroll
        for (int j = 0; j < 6; j++)
            bfr[j] = *(const short8*)(gBp + (size_t)j * 16 * 384 + ks * 32);
        short8 af[3];
#pragma unroll
        for (int i = 0; i < 3; i++)
            af[i] = *(const short8*)&SMEM[(ks * 3 + i) * 512 + aoffP];
#pragma unroll
        for (int i = 0; i < 3; i++)
#pragma unroll
            for (int j = 0; j < 6; j++)
                pacc[i][j] = __builtin_amdgcn_mfma_f32_16x16x32_bf16(af[i], bfr[j], pacc[i][j], 0, 0, 0);
    }

    // ---- epilogue: scatter to out (window-reverse + roll), rows<36 ----
    float bpv[6];
#pragma unroll
    for (int j = 0; j < 6; j++) bpv[j] = bp[wave * 96 + j * 16 + l15];
#pragma unroll
    for (int i = 0; i < 3; i++)
#pragma unroll
        for (int r = 0; r < 4; r++) {
            int R = i * 16 + quad * 4 + r;
            if (R < 36) {
                float* orow = out + rowOut36[R];
#pragma unroll
                for (int j = 0; j < 6; j++)
                    orow[wave * 96 + j * 16 + l15] = pacc[i][j][r] + bpv[j];
            }
        }
}

} // namespace

extern "C" void kernel_launch(void* const* d_in, const int* in_sizes, int n_in,
                              void* d_out, int out_size, void* d_ws, size_t ws_size,
                              hipStream_t stream)
{
    const float* x  = (const float*)d_in[0];
    const float* wq = (const float*)d_in[1];
    const float* bq = (const float*)d_in[2];
    const float* wp = (const float*)d_in[3];
    const float* bp = (const float*)d_in[4];
    float* out = (float*)d_out;

    const size_t HE   = (size_t)Mn * NHn * HEADS_E;      // 28.3M elems per tensor
    const size_t XG_E = (size_t)ROWS * Dm;               // == HE
    unsigned short* qh  = (unsigned short*)d_ws;
    unsigned short* kh  = qh + HE;   // qf t=2 row overrun (<=1.2KB) lands in kh: finite bf16
    unsigned short* vh  = kh + HE;   // kf overrun lands in vh: finite bf16
    unsigned short* xg  = vh + HE;
    unsigned short* wqT = xg + XG_E;
    unsigned short* wpT = wqT + (size_t)K3 * Dm;

    prep_w   <<<(K3 * Dm + Dm * Dm + 255) / 256, 256, 0, stream>>>(wq, wp, wqT, wpT);
    gather_x <<<ROWS * (Dm / 4) / 256,            256, 0, stream>>>(x, xg);
    qkv_mfma <<<(ROWS / 128) * (K3 / 128),        256, 0, stream>>>(xg, wqT, bq, qh, kh, vh);
    attn_proj<<<Mn,                               256, 0, stream>>>(qh, kh, vh, wpT, bp, out);
}

// Round 16
// 409.368 us; speedup vs baseline: 1.1792x; 1.1792x over previous
//
#include <hip/hip_runtime.h>
#include <hip/hip_bf16.h>

namespace {

constexpr int Bn   = 32;
constexpr int IMG  = 48;
constexpr int Dm   = 384;
constexpr int NHn  = 8;
constexpr int WSn  = 6;
constexpr int NWn  = 64;          // 8x8 windows
constexpr int Mn   = Bn * NWn;    // 2048 windows
constexpr int Vn   = 36;          // tokens per window
constexpr int ROWS = Mn * Vn;     // 73728 token rows
constexpr int K3   = 3 * Dm;      // 1152
constexpr int HEADS_E = Vn * 48;  // 1728 elems per (m,h) tile
constexpr int GATHER_BLOCKS = ROWS * (Dm / 4) / 256;   // 27648
constexpr int PREP_BLOCKS   = (K3 * Dm + Dm * Dm) / 256; // 2304
constexpr float SCALE = 0.14433756729740643f;  // 48^-0.5

using short8 = __attribute__((ext_vector_type(8))) short;
using f32x4  = __attribute__((ext_vector_type(4))) float;

__device__ __forceinline__ unsigned short f2bf(float f) {
    unsigned u = __float_as_uint(f);
    u += 0x7FFFu + ((u >> 16) & 1u);   // RNE
    return (unsigned short)(u >> 16);
}

// 64-slot involution: low 3 bits ^= high 3 bits. Self-inverse.
// Verified R5/R6/R9: SQ_LDS_BANK_CONFLICT 7.96M -> 0, results exact.
__device__ __forceinline__ int invol(int f) {
    return (f & 56) | ((f ^ (f >> 3)) & 7);
}

// async global->LDS, 16B per lane; LDS dest = wave-uniform base + lane*16
__device__ __forceinline__ void gl_lds16(const unsigned short* g, unsigned short* l) {
    __builtin_amdgcn_global_load_lds(
        (const __attribute__((address_space(1))) unsigned int*)g,
        (__attribute__((address_space(3))) unsigned int*)l, 16, 0, 0);
}

// row -> gathered source base (roll(-3) + window partition), in elements
__device__ __forceinline__ int gather_base(int row) {
    int m = row / Vn, v = row - m * Vn;
    int b = m >> 6, w = m & 63;
    int wh = w >> 3, ww = w & 7;
    int gh = wh * WSn + v / WSn;
    int gw = ww * WSn + v % WSn;
    int fi = (gh + 3) % IMG;
    int fj = (gw + 3) % IMG;
    return ((b * IMG + fi) * IMG + fj) * Dm;
}

// region id of token t in window (wh, ww)
__device__ __forceinline__ int region_id(int t, int wh, int ww) {
    int hi = (wh == 7) ? ((t / 6) < 3) : 1;
    int lo = (ww == 7) ? ((t % 6) < 3) : 1;
    return (hi << 1) | lo;
}

// ---------------------------------------------------------------------------
// gather_prep (MERGED gather_x + prep_w -> one fewer launch; the two jobs
// have disjoint outputs and no mutual ordering; branch is block-uniform).
// blocks [0, 27648): xg[row][k] = bf16(x[gathered(row)][k])
// blocks [27648, 29952): wqT/wpT transposed bf16 weight prep
// ---------------------------------------------------------------------------
__global__ __launch_bounds__(256)
void gather_prep(const float* __restrict__ x,
                 const float* __restrict__ wq, const float* __restrict__ wp,
                 unsigned short* __restrict__ xg,
                 unsigned short* __restrict__ wqT, unsigned short* __restrict__ wpT)
{
    if (blockIdx.x < GATHER_BLOCKS) {
        int idx = blockIdx.x * 256 + threadIdx.x;      // ROWS*96 total
        int row = idx / 96;
        int c4  = (idx - row * 96) * 4;
        float4 v = *(const float4*)(x + (size_t)gather_base(row) + c4);
        ushort4 o;
        o.x = f2bf(v.x); o.y = f2bf(v.y); o.z = f2bf(v.z); o.w = f2bf(v.w);
        *(ushort4*)(xg + (size_t)row * Dm + c4) = o;
    } else {
        int idx = (blockIdx.x - GATHER_BLOCKS) * 256 + threadIdx.x;
        if (idx < K3 * Dm) {
            int n = idx / Dm, k = idx - n * Dm;
            wqT[idx] = f2bf(wq[(size_t)k * K3 + n]);
        } else {
            int i2 = idx - K3 * Dm;
            if (i2 < Dm * Dm) {
                int n = i2 / Dm, k = i2 - n * Dm;
                wpT[i2] = f2bf(wp[(size_t)k * Dm + n]);
            }
        }
    }
}

// ---------------------------------------------------------------------------
// qkv_mfma: R4 champion structure (single 16KB As/Bs, drain-0 two-barrier
// K-loop -- the best-wall config) + invol swizzle at CONSTANT LDS (permuted
// gl_lds source, linear dest, swizzled fragment reads): removes the 7.96M
// conflict cycles R4 carried, with zero occupancy change. All fancier
// schedules (2-phase, counted-vmcnt 3-bubuf) measured null at 115-118us.
// XCD-swizzled blockIdx: one A-tile's 9-block nT sweep stays on one XCD.
// ---------------------------------------------------------------------------
__global__ __launch_bounds__(256)
void qkv_mfma(const unsigned short* __restrict__ xg,
              const unsigned short* __restrict__ wqT,
              const float* __restrict__ bq,
              unsigned short* __restrict__ qh,
              unsigned short* __restrict__ kh,
              unsigned short* __restrict__ vh)
{
    __shared__ __align__(16) unsigned short As[128 * 32];   // 8 KB
    __shared__ __align__(16) unsigned short Bs[128 * 32];   // 8 KB

    const int tid  = threadIdx.x;
    const int wave = tid >> 6, lane = tid & 63;
    const int quad = lane >> 4, l15 = lane & 15;
    // bijective XCD swizzle: grid = 5184 = 8 * 648
    const int id = (blockIdx.x & 7) * 648 + (blockIdx.x >> 3);
    const int nT = id % (K3 / 128);   // 9
    const int mT = id / (K3 / 128);
    const int rowA0 = mT * 128, rowB0 = nT * 128;

    // involution-permuted global staging source (linear LDS dest)
    const int fS  = invol(lane);
    const int rS  = fS >> 2;
    const int kcS = (fS & 3) * 8;
    const unsigned short* gA = xg  + (size_t)(rowA0 + wave * 32 + rS) * Dm + kcS;
    const unsigned short* gB = wqT + (size_t)(rowB0 + wave * 32 + rS) * Dm + kcS;
    unsigned short* lA0 = &As[(wave * 32) * 32];
    unsigned short* lA1 = &As[(wave * 32 + 16) * 32];
    unsigned short* lB0 = &Bs[(wave * 32) * 32];
    unsigned short* lB1 = &Bs[(wave * 32 + 16) * 32];

    // loop-invariant swizzled fragment read offsets
    const int wm = wave >> 1, wn = wave & 1;
    int aoff[4], boff[4];
#pragma unroll
    for (int i = 0; i < 4; i++) {
        int R = wm * 64 + i * 16 + l15;
        aoff[i] = (R >> 4) * 512 + invol((R & 15) * 4 + quad) * 8;
        int S = wn * 64 + i * 16 + l15;
        boff[i] = (S >> 4) * 512 + invol((S & 15) * 4 + quad) * 8;
    }

    f32x4 acc[4][4];
#pragma unroll
    for (int i = 0; i < 4; i++)
#pragma unroll
        for (int j = 0; j < 4; j++) acc[i][j] = (f32x4){0.f, 0.f, 0.f, 0.f};

    for (int k0 = 0; k0 < Dm; k0 += 32) {
        __syncthreads();
        gl_lds16(gA + k0, lA0);
        gl_lds16(gA + 16 * Dm + k0, lA1);
        gl_lds16(gB + k0, lB0);
        gl_lds16(gB + 16 * Dm + k0, lB1);
        __syncthreads();
        short8 af[4], bfr[4];
#pragma unroll
        for (int i = 0; i < 4; i++) af[i]  = *(const short8*)&As[aoff[i]];
#pragma unroll
        for (int j = 0; j < 4; j++) bfr[j] = *(const short8*)&Bs[boff[j]];
#pragma unroll
        for (int i = 0; i < 4; i++)
#pragma unroll
            for (int j = 0; j < 4; j++)
                acc[i][j] = __builtin_amdgcn_mfma_f32_16x16x32_bf16(af[i], bfr[j], acc[i][j], 0, 0, 0);
    }

    unsigned short* outb = (nT < 3) ? qh : (nT < 6) ? kh : vh;
    const int csub = (nT < 3) ? 0 : (nT < 6) ? 384 : 768;
#pragma unroll
    for (int j = 0; j < 4; j++) {
        int col = rowB0 + wn * 64 + j * 16 + l15;
        float b = bq[col];
        int c  = col - csub;               // 0..383 within section
        int hh = c / 48, dd = c - hh * 48;
#pragma unroll
        for (int i = 0; i < 4; i++) {
#pragma unroll
            for (int r = 0; r < 4; r++) {
                int row = rowA0 + wm * 64 + i * 16 + quad * 4 + r;
                int mm = row / 36, vv = row - mm * 36;
                outb[((size_t)(mm * 8 + hh) * 36 + vv) * 48 + dd] = f2bf(acc[i][j][r] + b);
            }
        }
    }
}

// ---------------------------------------------------------------------------
// attn_mfma: one wave per (window m, head h). R4/R9 measured body, unchanged.
// (Fusion with proj measured wall-negative across R10-R12; reverted.)
// ---------------------------------------------------------------------------
__global__ __launch_bounds__(256)
void attn_mfma(const unsigned short* __restrict__ qh,
               const unsigned short* __restrict__ kh,
               const unsigned short* __restrict__ vh,
               unsigned short* __restrict__ att)
{
    __shared__ __align__(16) unsigned short Pl[4][48 * 56];   // 21.5 KB
    __shared__ __align__(16) unsigned short Vt[4][48 * 64];   // 24.6 KB

    const int tid  = threadIdx.x;
    const int wave = tid >> 6, lane = tid & 63;
    const int quad = lane >> 4, l15 = lane & 15;
    const int W = blockIdx.x * 4 + wave;
    const int m = W >> 3, h = W & 7;
    const int w = m & 63, wh = w >> 3, ww = w & 7;
    const bool need_mask = (wh == 7) || (ww == 7);   // 49/64 windows skip masking

    const short8 zf = {0, 0, 0, 0, 0, 0, 0, 0};

    // zero Vt so tokens [36,64) read back as 0.0 (6 x short8 per thread)
    {
        short8* vz = (short8*)&Vt[0][0];
#pragma unroll
        for (int z = 0; z < 6; z++) vz[z * 256 + tid] = zf;
    }
    __syncthreads();

    const size_t hb = (size_t)(m * 8 + h) * HEADS_E;

    // ---- Q/K fragments straight from global (per-head contiguous) ----
    const unsigned short* qb = qh + hb;
    const unsigned short* kb = kh + hb;
    short8 qf[3][2], kf[3][2];
#pragma unroll
    for (int t = 0; t < 3; t++) {
        const unsigned short* qr = qb + (t * 16 + l15) * 48;
        qf[t][0] = *(const short8*)(qr + quad * 8);
        qf[t][1] = (quad < 2) ? *(const short8*)(qr + 32 + quad * 8) : zf;  // k>=48 zeroed (A side)
        const unsigned short* kr = kb + (t * 16 + l15) * 48;
        kf[t][0] = *(const short8*)(kr + quad * 8);
        kf[t][1] = *(const short8*)(kr + 32 + quad * 8);                    // garbage ok (B side)
    }

    // ---- stage V -> LDS transposed (slot-rotated); tokens >= 36 stay 0 ----
    unsigned short* vws = &Vt[wave][0];
    {
        const unsigned short* vb = vh + hb;
#pragma unroll
        for (int p = 0; p < 4; p++) {
            int c = p * 64 + lane;                 // 216 16B-chunks = 36x48
            if (c < 216) {
                short8 vv = *(const short8*)(vb + c * 8);
                int v  = c / 6, d0 = (c - v * 6) * 8;
                int g  = v >> 3, v7 = v & 7;
#pragma unroll
                for (int jj = 0; jj < 8; jj++) {
                    int d = d0 + jj;
                    int slot = (g + (d & 7) + (d >> 3)) & 7;
                    vws[d * 64 + slot * 8 + v7] = (unsigned short)vv[jj];
                }
            }
        }
    }

    // ---- QK^T ----
    f32x4 acc[3][3];
#pragma unroll
    for (int i = 0; i < 3; i++)
#pragma unroll
        for (int j = 0; j < 3; j++) acc[i][j] = (f32x4){0.f, 0.f, 0.f, 0.f};
    __builtin_amdgcn_s_setprio(1);
#pragma unroll
    for (int i = 0; i < 3; i++)
#pragma unroll
        for (int j = 0; j < 3; j++) {
            acc[i][j] = __builtin_amdgcn_mfma_f32_16x16x32_bf16(qf[i][0], kf[j][0], acc[i][j], 0, 0, 0);
            acc[i][j] = __builtin_amdgcn_mfma_f32_16x16x32_bf16(qf[i][1], kf[j][1], acc[i][j], 0, 0, 0);
        }
    __builtin_amdgcn_s_setprio(0);

    // ---- mask + exp + row-sum (butterfly over the 16-lane col group) ----
#pragma unroll
    for (int i = 0; i < 3; i++) {
        float rs[4] = {0.f, 0.f, 0.f, 0.f};
        if (need_mask) {
#pragma unroll
            for (int j = 0; j < 3; j++) {
                int C = j * 16 + l15;
                int idc = region_id(C, wh, ww);
#pragma unroll
                for (int r = 0; r < 4; r++) {
                    int R = i * 16 + quad * 4 + r;
                    int idr = region_id(R, wh, ww);
                    float s = acc[i][j][r] * SCALE;
                    s = (C >= 36 || idr != idc) ? -1e30f : fminf(s, 30.f);
                    float e = __expf(s);
                    acc[i][j][r] = e;
                    rs[r] += e;
                }
            }
        } else {
#pragma unroll
            for (int j = 0; j < 3; j++) {
                int C = j * 16 + l15;
#pragma unroll
                for (int r = 0; r < 4; r++) {
                    float s = acc[i][j][r] * SCALE;
                    s = (C >= 36) ? -1e30f : fminf(s, 30.f);
                    float e = __expf(s);
                    acc[i][j][r] = e;
                    rs[r] += e;
                }
            }
        }
#pragma unroll
        for (int r = 0; r < 4; r++) {
#pragma unroll
            for (int d = 1; d < 16; d <<= 1) rs[r] += __shfl_xor(rs[r], d, 16);
            rs[r] = 1.f / rs[r];
        }
#pragma unroll
        for (int j = 0; j < 3; j++)
#pragma unroll
            for (int r = 0; r < 4; r++) {
                int R = i * 16 + quad * 4 + r;
                int C = j * 16 + l15;
                Pl[wave][R * 56 + C] = f2bf(acc[i][j][r] * rs[r]);
            }
    }
    __syncthreads();   // orders Pl + Vt writes before fragment reads

    // ---- PV: A = P (LDS), B = V^T (LDS, slot-rotated) ----
    short8 pf[3][2], vf[3][2];
#pragma unroll
    for (int t = 0; t < 3; t++) {
        const unsigned short* pr = &Pl[wave][(t * 16 + l15) * 56];
        pf[t][0] = *(const short8*)(pr + quad * 8);
        pf[t][1] = (quad < 2) ? *(const short8*)(pr + 32 + quad * 8) : zf;  // tokens>=48 zero
        int d  = t * 16 + l15;
        int sb = (d & 7) + (d >> 3);
        vf[t][0] = *(const short8*)(vws + d * 64 + (((quad + sb) & 7) * 8));      // tokens quad*8..+8
        vf[t][1] = *(const short8*)(vws + d * 64 + (((quad + 4 + sb) & 7) * 8));  // tokens 32+quad*8..+8
    }
    f32x4 oacc[3][3];
#pragma unroll
    for (int i = 0; i < 3; i++)
#pragma unroll
        for (int j = 0; j < 3; j++) oacc[i][j] = (f32x4){0.f, 0.f, 0.f, 0.f};
    __builtin_amdgcn_s_setprio(1);
#pragma unroll
    for (int i = 0; i < 3; i++)
#pragma unroll
        for (int j = 0; j < 3; j++) {
            oacc[i][j] = __builtin_amdgcn_mfma_f32_16x16x32_bf16(pf[i][0], vf[j][0], oacc[i][j], 0, 0, 0);
            oacc[i][j] = __builtin_amdgcn_mfma_f32_16x16x32_bf16(pf[i][1], vf[j][1], oacc[i][j], 0, 0, 0);
        }
    __builtin_amdgcn_s_setprio(0);

    // ---- store: att[(m*36+R)*384 + h*48 + d], rows >= 36 discarded ----
#pragma unroll
    for (int i = 0; i < 3; i++)
#pragma unroll
        for (int r = 0; r < 4; r++) {
            int R = i * 16 + quad * 4 + r;
            if (R < 36) {
#pragma unroll
                for (int j = 0; j < 3; j++)
                    att[((size_t)m * 36 + R) * Dm + h * 48 + j * 16 + l15] = f2bf(oacc[i][j][r]);
            }
        }
}

// ---------------------------------------------------------------------------
// proj_mfma: out = att @ wpT^T + bp, scattered (window-reverse + roll(+3)).
// R4 champion structure (16KB single-buffer drain-0) + invol swizzle at
// constant LDS. XCD-swizzled.
// ---------------------------------------------------------------------------
__global__ __launch_bounds__(256)
void proj_mfma(const unsigned short* __restrict__ att,
               const unsigned short* __restrict__ wpT,
               const float* __restrict__ bp,
               float* __restrict__ out)
{
    __shared__ __align__(16) unsigned short As[128 * 32];
    __shared__ __align__(16) unsigned short Bs[128 * 32];
    __shared__ int rowOut[128];

    const int tid  = threadIdx.x;
    const int wave = tid >> 6, lane = tid & 63;
    const int quad = lane >> 4, l15 = lane & 15;
    // bijective XCD swizzle: grid = 1728 = 8 * 216
    const int id = (blockIdx.x & 7) * 216 + (blockIdx.x >> 3);
    const int nT = id % (Dm / 128);   // 3
    const int mT = id / (Dm / 128);
    const int rowA0 = mT * 128, rowB0 = nT * 128;

    if (tid < 128) rowOut[tid] = gather_base(rowA0 + tid);

    const int fS  = invol(lane);
    const int rS  = fS >> 2;
    const int kcS = (fS & 3) * 8;
    const unsigned short* gA = att + (size_t)(rowA0 + wave * 32 + rS) * Dm + kcS;
    const unsigned short* gB = wpT + (size_t)(rowB0 + wave * 32 + rS) * Dm + kcS;
    unsigned short* lA0 = &As[(wave * 32) * 32];
    unsigned short* lA1 = &As[(wave * 32 + 16) * 32];
    unsigned short* lB0 = &Bs[(wave * 32) * 32];
    unsigned short* lB1 = &Bs[(wave * 32 + 16) * 32];

    const int wm = wave >> 1, wn = wave & 1;
    int aoff[4], boff[4];
#pragma unroll
    for (int i = 0; i < 4; i++) {
        int R = wm * 64 + i * 16 + l15;
        aoff[i] = (R >> 4) * 512 + invol((R & 15) * 4 + quad) * 8;
        int S = wn * 64 + i * 16 + l15;
        boff[i] = (S >> 4) * 512 + invol((S & 15) * 4 + quad) * 8;
    }

    f32x4 acc[4][4];
#pragma unroll
    for (int i = 0; i < 4; i++)
#pragma unroll
        for (int j = 0; j < 4; j++) acc[i][j] = (f32x4){0.f, 0.f, 0.f, 0.f};

    for (int k0 = 0; k0 < Dm; k0 += 32) {
        __syncthreads();
        gl_lds16(gA + k0, lA0);
        gl_lds16(gA + 16 * Dm + k0, lA1);
        gl_lds16(gB + k0, lB0);
        gl_lds16(gB + 16 * Dm + k0, lB1);
        __syncthreads();
        short8 af[4], bfr[4];
#pragma unroll
        for (int i = 0; i < 4; i++) af[i]  = *(const short8*)&As[aoff[i]];
#pragma unroll
        for (int j = 0; j < 4; j++) bfr[j] = *(const short8*)&Bs[boff[j]];
#pragma unroll
        for (int i = 0; i < 4; i++)
#pragma unroll
            for (int j = 0; j < 4; j++)
                acc[i][j] = __builtin_amdgcn_mfma_f32_16x16x32_bf16(af[i], bfr[j], acc[i][j], 0, 0, 0);
    }

#pragma unroll
    for (int j = 0; j < 4; j++) {
        int col = rowB0 + wn * 64 + j * 16 + l15;
        float b = bp[col];
#pragma unroll
        for (int i = 0; i < 4; i++) {
#pragma unroll
            for (int r = 0; r < 4; r++) {
                int lrow = wm * 64 + i * 16 + quad * 4 + r;
                out[(size_t)rowOut[lrow] + col] = acc[i][j][r] + b;
            }
        }
    }
}

} // namespace

extern "C" void kernel_launch(void* const* d_in, const int* in_sizes, int n_in,
                              void* d_out, int out_size, void* d_ws, size_t ws_size,
                              hipStream_t stream)
{
    const float* x  = (const float*)d_in[0];
    const float* wq = (const float*)d_in[1];
    const float* bq = (const float*)d_in[2];
    const float* wp = (const float*)d_in[3];
    const float* bp = (const float*)d_in[4];
    float* out = (float*)d_out;

    const size_t HE   = (size_t)Mn * NHn * HEADS_E;      // 28.3M elems per tensor
    const size_t XG_E = (size_t)ROWS * Dm;               // == HE
    unsigned short* qh  = (unsigned short*)d_ws;
    unsigned short* kh  = qh + HE;   // qf t=2 row overrun (<=1.2KB) lands in kh: finite bf16
    unsigned short* vh  = kh + HE;   // kf overrun lands in vh: finite bf16
    unsigned short* xg  = vh + HE;
    unsigned short* att = xg;        // alias: xg dead after qkv_mfma
    unsigned short* wqT = xg + XG_E;
    unsigned short* wpT = wqT + (size_t)K3 * Dm;

    gather_prep<<<GATHER_BLOCKS + PREP_BLOCKS, 256, 0, stream>>>(x, wq, wp, xg, wqT, wpT);
    qkv_mfma   <<<(ROWS / 128) * (K3 / 128),   256, 0, stream>>>(xg, wqT, bq, qh, kh, vh);
    attn_mfma  <<<(Mn * NHn) / 4,              256, 0, stream>>>(qh, kh, vh, att);
    proj_mfma  <<<(ROWS / 128) * (Dm / 128),   256, 0, stream>>>(att, wpT, bp, out);
}